// Round 2
// baseline (295.821 us; speedup 1.0000x reference)
//
#include <hip/hip_runtime.h>

namespace {

constexpr int B  = 16;
constexpr int D  = 128;
constexpr int C  = 6;
constexpr int H  = 128;
constexpr int W  = 128;
constexpr int HWC = H * W;          // 16384
constexpr int HO = 512, WO = 512;   // 4x upsample
constexpr int TILE = 64;            // pixels per LDS tile
constexpr int TPB  = 4;             // tiles per block (block owns 256 contiguous px)

// float4-granular XOR swizzle: conflict-free for 2a (px-parallel) reads,
// keeps 16B chunks intact for b128 stores and 2b px-chunk reads.
__device__ __forceinline__ int sw(int d, int px) {
  return px ^ (d & 60) ^ (((d >> 5) & 1) << 4);
}

// ---------------------------------------------------------------------------
// Fused K1+K2: one HBM pass over assp.
// LDS-pipe diet vs prior version: cls_w/cls_b come from scalar K$ loads
// (wave-uniform d => s_load), NOT LDS (-192 LDS reads/thread/tile);
// 2b reads are ds_read_b128 over 4-px chunks (32 b32 -> 8 b128).
// ---------------------------------------------------------------------------
__global__ __launch_bounds__(256) void k_fused(const float* __restrict__ assp,
                                               const float* __restrict__ cls_w,
                                               const float* __restrict__ cls_b,
                                               float* __restrict__ sums,
                                               int* __restrict__ counts,
                                               float* __restrict__ x) {
  __shared__ float tile[D * TILE];      // 32 KB, float4-swizzled
  __shared__ float red[4 * C * TILE];   // 6 KB (reused as part[] in epilogue)

  const int t  = threadIdx.x;
  const int b  = blockIdx.y;
  const int lane = t & 63;
  const int wv   = t >> 6;                               // wave id = d-quarter
  const int wvu  = __builtin_amdgcn_readfirstlane(wv);   // force SGPR => s_load
  const int d2b  = t & 127;       // d owned in 2b
  const int h2b  = t >> 7;        // px-half owned in 2b
  const int sr   = t >> 4;        // staging base row (0..15)
  const int spx  = (t & 15) * 4;  // staging px4

  float acc2b[C] = {0.f, 0.f, 0.f, 0.f, 0.f, 0.f};
  int   cnt_run  = 0;             // wave0 lane c accumulates count of class c

  const int hw_base = blockIdx.x * (TILE * TPB);
  const float* bbase = assp + ((size_t)b * D) * HWC + hw_base;

  // ---- preload tile 0 into registers ----
  float4 v[8];
#pragma unroll
  for (int j = 0; j < 8; ++j)
    v[j] = *(const float4*)(bbase + (size_t)(sr + 16 * j) * HWC + spx);

  const float* wsr = cls_w + wvu * 32;   // wave's d-quarter; row-c stride = D

  for (int it = 0; it < TPB; ++it) {
    const int hw0 = hw_base + it * TILE;

    // ---- store prefetched registers -> LDS (swizzled b128) ----
#pragma unroll
    for (int j = 0; j < 8; ++j) {
      int d = sr + 16 * j;
      *(float4*)&tile[d * TILE + sw(d, spx)] = v[j];
    }
    __syncthreads();

    // ---- issue next tile's global loads; they fly under 2a/2b ----
    if (it + 1 < TPB) {
      const float* nb = bbase + (it + 1) * TILE;
#pragma unroll
      for (int j = 0; j < 8; ++j)
        v[j] = *(const float4*)(nb + (size_t)(sr + 16 * j) * HWC + spx);
    }

    // ---- phase 2a: dots (px = lane, d-quarter = wv); weights via s_load ----
    {
      float a[C] = {0.f, 0.f, 0.f, 0.f, 0.f, 0.f};
#pragma unroll
      for (int dd = 0; dd < 32; ++dd) {
        int d = wvu * 32 + dd;
        float vv = tile[d * TILE + sw(d, lane)];
#pragma unroll
        for (int c = 0; c < C; ++c) a[c] += vv * wsr[c * D + dd];
      }
#pragma unroll
      for (int c = 0; c < C; ++c) red[(wvu * C + c) * TILE + lane] = a[c];
    }
    __syncthreads();

    // ---- finalize (replicated in all waves): class of px = lane ----
    int cls;
    {
      float s[C];
#pragma unroll
      for (int c = 0; c < C; ++c)
        s[c] = red[(0 * C + c) * TILE + lane] + red[(1 * C + c) * TILE + lane]
             + red[(2 * C + c) * TILE + lane] + red[(3 * C + c) * TILE + lane];
      float bv = s[0] + cls_b[0]; cls = 0;      // first-wins == jnp.argmax
#pragma unroll
      for (int c = 1; c < C; ++c) {
        float pv = s[c] + cls_b[c];
        if (pv > bv) { bv = pv; cls = c; }
      }
      if (wv == 0) {
        const float inv12 = 1.0f / 12.0f;
        float* xb = x + ((size_t)b * C) * HWC + hw0 + lane;
#pragma unroll
        for (int c = 0; c < C; ++c) xb[(size_t)c * HWC] = s[c] * inv12 + cls_b[c];
#pragma unroll
        for (int c = 0; c < C; ++c) {
          unsigned long long m = __ballot(cls == c);
          if (lane == c) cnt_run += (int)__popcll(m);
        }
      }
    }

    // ---- phase 2b: per-class sums, b128 over 4-px chunks ----
#pragma unroll
    for (int i = 0; i < 8; ++i) {
      int px4 = h2b * 32 + 4 * i;
      float4 u = *(const float4*)&tile[d2b * TILE + sw(d2b, px4)];
      int c0 = __shfl(cls, px4 + 0, 64);
      int c1 = __shfl(cls, px4 + 1, 64);
      int c2 = __shfl(cls, px4 + 2, 64);
      int c3 = __shfl(cls, px4 + 3, 64);
#pragma unroll
      for (int cc = 0; cc < C; ++cc) {    // px-sequential adds (order-preserving)
        acc2b[cc] += (c0 == cc) ? u.x : 0.f;
        acc2b[cc] += (c1 == cc) ? u.y : 0.f;
        acc2b[cc] += (c2 == cc) ? u.z : 0.f;
        acc2b[cc] += (c3 == cc) ? u.w : 0.f;
      }
    }
    __syncthreads();                      // before next tile overwrites LDS
  }

  // ---- block epilogue: pair-reduce h halves, one atomic burst per block ----
  float* part = red;                      // reuse (>=768 floats)
  if (h2b == 1) {
#pragma unroll
    for (int c = 0; c < C; ++c) part[c * D + d2b] = acc2b[c];
  }
  __syncthreads();
  if (h2b == 0) {
#pragma unroll
    for (int c = 0; c < C; ++c) {
      float s = acc2b[c] + part[c * D + d2b];
      atomicAdd(&sums[((size_t)b * C + c) * D + d2b], s);
    }
  }
  if (wv == 0 && lane < C) atomicAdd(&counts[b * C + lane], cnt_run);
}

// ---------------------------------------------------------------------------
// K3: per dropped pixel: protoC on the fly from sums/counts, nearest proto
// (first-wins argmin == over the 12=2x6 duplicated list), patch x directly.
// one wave per (b,p); lane owns d and d+64
// ---------------------------------------------------------------------------
__global__ void k_patch(const float* __restrict__ assp,
                        const float* __restrict__ sums,
                        const int* __restrict__ counts,
                        const float* __restrict__ cls_w,
                        const float* __restrict__ cls_b,
                        const int* __restrict__ px,
                        const int* __restrict__ py,
                        int P,
                        float* __restrict__ x) {
  int bp = blockIdx.x;
  int b = bp / P, p = bp % P;
  int hw = px[p] * W + py[p];
  int lane = threadIdx.x;                  // 64 threads = 1 wave
  const float* fbase = assp + ((size_t)b * D) * HWC + hw;

  float f0 = fbase[(size_t)lane * HWC];
  float f1 = fbase[(size_t)(lane + 64) * HWC];

  float pv0[C], pv1[C], ds[C];
#pragma unroll
  for (int c = 0; c < C; ++c) {
    float cnt = (float)counts[b * C + c];
    float s0 = sums[((size_t)b * C + c) * D + lane];
    float s1 = sums[((size_t)b * C + c) * D + lane + 64];
    float q0 = (cnt > 0.f) ? s0 / (cnt + 1e-5f) : 0.f;
    float q1 = (cnt > 0.f) ? s1 / (cnt + 1e-5f) : 0.f;
    pv0[c] = q0; pv1[c] = q1;
    float e0 = q0 - f0, e1 = q1 - f1;
    float tt = e0 * e0 + e1 * e1;
#pragma unroll
    for (int off = 32; off >= 1; off >>= 1) tt += __shfl_xor(tt, off, 64);
    ds[c] = tt;                            // identical on all lanes
  }
  int best = 0; float bv = ds[0];          // first-wins ties == jnp.argmin
#pragma unroll
  for (int c = 1; c < C; ++c)
    if (ds[c] < bv) { bv = ds[c]; best = c; }

  float v0 = 0.f, v1 = 0.f;                // select without dynamic indexing
#pragma unroll
  for (int c = 0; c < C; ++c) {
    if (best == c) { v0 = pv0[c]; v1 = pv1[c]; }
  }

  float myx = 0.f;
#pragma unroll
  for (int c = 0; c < C; ++c) {
    float tt = v0 * cls_w[c * D + lane] + v1 * cls_w[c * D + lane + 64];
#pragma unroll
    for (int off = 32; off >= 1; off >>= 1) tt += __shfl_xor(tt, off, 64);
    float val = tt * (1.0f / 12.0f) + cls_b[c];
    if (lane == c) myx = val;
  }
  if (lane < C) x[((size_t)b * C + lane) * HWC + hw] = myx;
}

// ---------------------------------------------------------------------------
// K4: bilinear 4x upsample. Weights via exact integer math; <=3 input rows
// staged in LDS; 2 output rows per block; float4 coalesced stores.
// ---------------------------------------------------------------------------
__global__ __launch_bounds__(256) void k_up(const float* __restrict__ x,
                                            float* __restrict__ out) {
  __shared__ float rows[3 * W];            // 1.5 KB

  const int t = threadIdx.x;
  const size_t base = (size_t)blockIdx.x * 1024;   // first linear output index
  const int bc = (int)(base >> 18);                // output image (b*C+c)
  const int Y0 = ((int)(base >> 9)) & (HO - 1);    // first of 2 output rows

  const int ry = (Y0 * (H - 1)) / (HO - 1);        // lowest needed input row

  if (t < 96) {
    int r  = t >> 5;                               // 0..2
    int xx = (t & 31) * 4;
    int rr = ry + r; if (rr > H - 1) rr = H - 1;
    *(float4*)&rows[r * W + xx] =
        *(const float4*)(x + (size_t)bc * HWC + (size_t)rr * W + xx);
  }
  __syncthreads();

  const int h  = t >> 7;                           // which output row
  const int tt = t & 127;                          // 4 consecutive X each
  const int Y  = Y0 + h;

  const int ynum = Y * (H - 1);
  const int yl   = ynum / (HO - 1);
  const float wy = (float)((double)(ynum - yl * (HO - 1)) * (1.0 / (HO - 1)));
  int yh = yl + 1; if (yh > H - 1) yh = H - 1;
  const float* r0 = &rows[(yl - ry) * W];
  const float* r1 = &rows[(yh - ry) * W];

  float o[4];
#pragma unroll
  for (int j = 0; j < 4; ++j) {
    int X   = 4 * tt + j;
    int num = X * (W - 1);
    int lo  = num / (WO - 1);
    float wx = (float)((double)(num - lo * (WO - 1)) * (1.0 / (WO - 1)));
    int hi = lo + 1; if (hi > W - 1) hi = W - 1;

    float v00 = r0[lo], v01 = r0[hi], v10 = r1[lo], v11 = r1[hi];
    o[j] = (1.f - wy) * ((1.f - wx) * v00 + wx * v01)
         +        wy  * ((1.f - wx) * v10 + wx * v11);
  }
  float4 o4 = {o[0], o[1], o[2], o[3]};
  *(float4*)(out + base + (size_t)h * WO + 4 * tt) = o4;
}

} // namespace

extern "C" void kernel_launch(void* const* d_in, const int* in_sizes, int n_in,
                              void* d_out, int out_size, void* d_ws, size_t ws_size,
                              hipStream_t stream) {
  // inputs: assp, cls_w, cls_b, key_w, key_b, query_w, query_b, px, py
  const float* assp  = (const float*)d_in[0];
  const float* cls_w = (const float*)d_in[1];
  const float* cls_b = (const float*)d_in[2];
  const int*   px    = (const int*)d_in[7];
  const int*   py    = (const int*)d_in[8];
  const int    P     = in_sizes[7];             // 102

  // workspace layout
  char* ws = (char*)d_ws;
  float* sums   = (float*)ws;                   // B*C*D = 49152 B
  int*   counts = (int*)(ws + 49152);           // B*C*4 = 384 B
  float* x      = (float*)(ws + 65536);         // B*C*HWC = 6 MB

  float* out = (float*)d_out;

  hipMemsetAsync(ws, 0, 49152 + 384, stream);
  k_fused<<<dim3(HWC / (TILE * TPB), B), 256, 0, stream>>>(assp, cls_w, cls_b,
                                                           sums, counts, x);
  k_patch<<<B * P, 64, 0, stream>>>(assp, sums, counts, cls_w, cls_b, px, py, P, x);
  k_up<<<(B * C * HO * WO) / 1024, 256, 0, stream>>>(x, out);
}

// Round 3
// 279.868 us; speedup vs baseline: 1.0570x; 1.0570x over previous
//
#include <hip/hip_runtime.h>

namespace {

constexpr int B  = 16;
constexpr int D  = 128;
constexpr int C  = 6;
constexpr int H  = 128;
constexpr int W  = 128;
constexpr int HWC = H * W;          // 16384
constexpr int HO = 512, WO = 512;   // 4x upsample
constexpr int CHUNK = 2048;         // px per wave in k_sum

// ---------------------------------------------------------------------------
// k_cls: px-ownership streaming pass. One thread per pixel.
//   - streams assp[b, :, px] (wave = 64 contiguous px -> 256B coalesced/instr)
//   - 6 dot-product accumulators in registers; weights via wave-uniform s_load
//   - argmax (first-wins == jnp.argmax), x = dot/12 + b, 1-byte class mask,
//     per-block class counts (one barrier, 6 atomics per block)
// Zero LDS data path, zero inter-wave dependencies -> latency-tolerant.
// ---------------------------------------------------------------------------
__global__ __launch_bounds__(256) void k_cls(const float* __restrict__ assp,
                                             const float* __restrict__ cls_w,
                                             const float* __restrict__ cls_b,
                                             float* __restrict__ x,
                                             unsigned char* __restrict__ mask,
                                             int* __restrict__ counts) {
  __shared__ int csh[4 * C];

  const int t  = threadIdx.x;
  const int b  = blockIdx.y;
  const int px = blockIdx.x * 256 + t;
  const int lane = t & 63;
  const int wv   = t >> 6;

  const float* col = assp + ((size_t)b * D) * HWC + px;

  float a[C] = {0.f, 0.f, 0.f, 0.f, 0.f, 0.f};
#pragma unroll 8
  for (int d = 0; d < D; ++d) {
    float vv = col[(size_t)d * HWC];
#pragma unroll
    for (int c = 0; c < C; ++c) a[c] += vv * cls_w[c * D + d];
  }

  // argmax, first-wins ties == jnp.argmax
  float bv = a[0] + cls_b[0];
  int cls = 0;
#pragma unroll
  for (int c = 1; c < C; ++c) {
    float pv = a[c] + cls_b[c];
    if (pv > bv) { bv = pv; cls = c; }
  }

  // x = pseudo/12 + bias  (softmax(...,axis=1).mean(axis=1) == 1/12)
  const float inv12 = 1.0f / 12.0f;
  float* xb = x + ((size_t)b * C) * HWC + px;
#pragma unroll
  for (int c = 0; c < C; ++c) xb[(size_t)c * HWC] = a[c] * inv12 + cls_b[c];

  mask[(size_t)b * HWC + px] = (unsigned char)cls;

  // per-wave ballots -> LDS -> one atomic burst per block
#pragma unroll
  for (int c = 0; c < C; ++c) {
    unsigned long long m = __ballot(cls == c);
    if (lane == 0) csh[wv * C + c] = (int)__popcll(m);
  }
  __syncthreads();
  if (t < C)
    atomicAdd(&counts[b * C + t],
              csh[0 * C + t] + csh[1 * C + t] + csh[2 * C + t] + csh[3 * C + t]);
}

// ---------------------------------------------------------------------------
// k_sum: d-ownership streaming pass. One wave per (b, d, 2048-px chunk).
//   - lanes stream 64 contiguous px per iter (coalesced), select via mask byte
//   - 6 register accumulators, butterfly reduce, one atomic per (c,d) per wave
// assp is L3-hot from k_cls -> FETCH_SIZE here measures L3 retention.
// ---------------------------------------------------------------------------
__global__ __launch_bounds__(256) void k_sum(const float* __restrict__ assp,
                                             const unsigned char* __restrict__ mask,
                                             float* __restrict__ sums) {
  const int t    = threadIdx.x;
  const int lane = t & 63;
  const int wv   = t >> 6;
  const int b    = blockIdx.z;
  const int d    = blockIdx.y * 4 + wv;
  const int px0  = blockIdx.x * CHUNK;

  const float* row = assp + ((size_t)b * D + d) * HWC + px0;
  const unsigned char* mrow = mask + (size_t)b * HWC + px0;

  float acc[C] = {0.f, 0.f, 0.f, 0.f, 0.f, 0.f};
#pragma unroll 4
  for (int i = 0; i < CHUNK / 64; ++i) {
    float vv = row[i * 64 + lane];
    int   c  = mrow[i * 64 + lane];
#pragma unroll
    for (int cc = 0; cc < C; ++cc) acc[cc] += (c == cc) ? vv : 0.f;
  }

  float out = 0.f;
#pragma unroll
  for (int cc = 0; cc < C; ++cc) {
    float s = acc[cc];
#pragma unroll
    for (int off = 32; off >= 1; off >>= 1) s += __shfl_xor(s, off, 64);
    if (lane == cc) out = s;
  }
  if (lane < C) atomicAdd(&sums[((size_t)b * C + lane) * D + d], out);
}

// ---------------------------------------------------------------------------
// K3: per dropped pixel: protoC on the fly from sums/counts, nearest proto
// (first-wins argmin == over the 12=2x6 duplicated list), patch x directly.
// one wave per (b,p); lane owns d and d+64
// ---------------------------------------------------------------------------
__global__ void k_patch(const float* __restrict__ assp,
                        const float* __restrict__ sums,
                        const int* __restrict__ counts,
                        const float* __restrict__ cls_w,
                        const float* __restrict__ cls_b,
                        const int* __restrict__ px,
                        const int* __restrict__ py,
                        int P,
                        float* __restrict__ x) {
  int bp = blockIdx.x;
  int b = bp / P, p = bp % P;
  int hw = px[p] * W + py[p];
  int lane = threadIdx.x;                  // 64 threads = 1 wave
  const float* fbase = assp + ((size_t)b * D) * HWC + hw;

  float f0 = fbase[(size_t)lane * HWC];
  float f1 = fbase[(size_t)(lane + 64) * HWC];

  float pv0[C], pv1[C], ds[C];
#pragma unroll
  for (int c = 0; c < C; ++c) {
    float cnt = (float)counts[b * C + c];
    float s0 = sums[((size_t)b * C + c) * D + lane];
    float s1 = sums[((size_t)b * C + c) * D + lane + 64];
    float q0 = (cnt > 0.f) ? s0 / (cnt + 1e-5f) : 0.f;
    float q1 = (cnt > 0.f) ? s1 / (cnt + 1e-5f) : 0.f;
    pv0[c] = q0; pv1[c] = q1;
    float e0 = q0 - f0, e1 = q1 - f1;
    float tt = e0 * e0 + e1 * e1;
#pragma unroll
    for (int off = 32; off >= 1; off >>= 1) tt += __shfl_xor(tt, off, 64);
    ds[c] = tt;                            // identical on all lanes
  }
  int best = 0; float bv = ds[0];          // first-wins ties == jnp.argmin
#pragma unroll
  for (int c = 1; c < C; ++c)
    if (ds[c] < bv) { bv = ds[c]; best = c; }

  float v0 = 0.f, v1 = 0.f;                // select without dynamic indexing
#pragma unroll
  for (int c = 0; c < C; ++c) {
    if (best == c) { v0 = pv0[c]; v1 = pv1[c]; }
  }

  float myx = 0.f;
#pragma unroll
  for (int c = 0; c < C; ++c) {
    float tt = v0 * cls_w[c * D + lane] + v1 * cls_w[c * D + lane + 64];
#pragma unroll
    for (int off = 32; off >= 1; off >>= 1) tt += __shfl_xor(tt, off, 64);
    float val = tt * (1.0f / 12.0f) + cls_b[c];
    if (lane == c) myx = val;
  }
  if (lane < C) x[((size_t)b * C + lane) * HWC + hw] = myx;
}

// ---------------------------------------------------------------------------
// K4: bilinear 4x upsample. Weights via exact integer math; <=3 input rows
// staged in LDS; 2 output rows per block; float4 coalesced stores.
// ---------------------------------------------------------------------------
__global__ __launch_bounds__(256) void k_up(const float* __restrict__ x,
                                            float* __restrict__ out) {
  __shared__ float rows[3 * W];            // 1.5 KB

  const int t = threadIdx.x;
  const size_t base = (size_t)blockIdx.x * 1024;   // first linear output index
  const int bc = (int)(base >> 18);                // output image (b*C+c)
  const int Y0 = ((int)(base >> 9)) & (HO - 1);    // first of 2 output rows

  const int ry = (Y0 * (H - 1)) / (HO - 1);        // lowest needed input row

  if (t < 96) {
    int r  = t >> 5;                               // 0..2
    int xx = (t & 31) * 4;
    int rr = ry + r; if (rr > H - 1) rr = H - 1;
    *(float4*)&rows[r * W + xx] =
        *(const float4*)(x + (size_t)bc * HWC + (size_t)rr * W + xx);
  }
  __syncthreads();

  const int h  = t >> 7;                           // which output row
  const int tt = t & 127;                          // 4 consecutive X each
  const int Y  = Y0 + h;

  const int ynum = Y * (H - 1);
  const int yl   = ynum / (HO - 1);
  const float wy = (float)((double)(ynum - yl * (HO - 1)) * (1.0 / (HO - 1)));
  int yh = yl + 1; if (yh > H - 1) yh = H - 1;
  const float* r0 = &rows[(yl - ry) * W];
  const float* r1 = &rows[(yh - ry) * W];

  float o[4];
#pragma unroll
  for (int j = 0; j < 4; ++j) {
    int X   = 4 * tt + j;
    int num = X * (W - 1);
    int lo  = num / (WO - 1);
    float wx = (float)((double)(num - lo * (WO - 1)) * (1.0 / (WO - 1)));
    int hi = lo + 1; if (hi > W - 1) hi = W - 1;

    float v00 = r0[lo], v01 = r0[hi], v10 = r1[lo], v11 = r1[hi];
    o[j] = (1.f - wy) * ((1.f - wx) * v00 + wx * v01)
         +        wy  * ((1.f - wx) * v10 + wx * v11);
  }
  float4 o4 = {o[0], o[1], o[2], o[3]};
  *(float4*)(out + base + (size_t)h * WO + 4 * tt) = o4;
}

} // namespace

extern "C" void kernel_launch(void* const* d_in, const int* in_sizes, int n_in,
                              void* d_out, int out_size, void* d_ws, size_t ws_size,
                              hipStream_t stream) {
  // inputs: assp, cls_w, cls_b, key_w, key_b, query_w, query_b, px, py
  const float* assp  = (const float*)d_in[0];
  const float* cls_w = (const float*)d_in[1];
  const float* cls_b = (const float*)d_in[2];
  const int*   px    = (const int*)d_in[7];
  const int*   py    = (const int*)d_in[8];
  const int    P     = in_sizes[7];             // 102

  // workspace layout
  char* ws = (char*)d_ws;
  float* sums            = (float*)ws;          // B*C*D = 49152 B
  int*   counts          = (int*)(ws + 49152);  // B*C*4 = 384 B
  float* x               = (float*)(ws + 65536);        // B*C*HWC*4 = 6 MB
  unsigned char* maskbuf = (unsigned char*)(ws + 8388608); // B*HWC = 256 KB

  float* out = (float*)d_out;

  hipMemsetAsync(ws, 0, 49152 + 384, stream);
  k_cls<<<dim3(HWC / 256, B), 256, 0, stream>>>(assp, cls_w, cls_b, x, maskbuf, counts);
  k_sum<<<dim3(HWC / CHUNK, D / 4, B), 256, 0, stream>>>(assp, maskbuf, sums);
  k_patch<<<B * P, 64, 0, stream>>>(assp, sums, counts, cls_w, cls_b, px, py, P, x);
  k_up<<<(B * C * HO * WO) / 1024, 256, 0, stream>>>(x, out);
}